// Round 8
// baseline (537.647 us; speedup 1.0000x reference)
//
#include <hip/hip_runtime.h>
#include <math.h>

#define B_ 2
#define S_ 1024
#define D_ 512
#define H_ 8
#define P_ 16
#define DH_ 64
#define HP3_ 384
#define CONCAT_ 896
#define CUTOFF 15.0f
#define SCALE_ 0.125f   // DH^-0.5 = 1/8
#define QT 32
#define KT 64
// LDS strides in dwords
#define SQS 68    // fp32 Q
#define SQPS 52   // fp32 QP
#define SKBS 36   // bf16 K (32 data dwords + 4 pad)
#define SKPS 52   // fp32 KP
#define SVBS 60   // bf16 V|VP (56 data dwords + 4 pad)
#define SWS 68    // fp32 weights

// ---------------------------------------------------------------- helpers
__device__ __forceinline__ float waveReduceSum(float v) {
#pragma unroll
    for (int o = 32; o; o >>= 1) v += __shfl_down(v, o, 64);
    return v;
}
__device__ __forceinline__ float dot4(float4 a, float4 b, float acc) {
    return fmaf(a.x, b.x, fmaf(a.y, b.y, fmaf(a.z, b.z, fmaf(a.w, b.w, acc))));
}
__device__ __forceinline__ unsigned rne16(float x) {   // fp32 -> bf16 (RNE)
    unsigned u = __float_as_uint(x);
    return (u + 0x7fffu + ((u >> 16) & 1u)) >> 16;
}
__device__ __forceinline__ uint2 pk4(float4 t) {
    return make_uint2(rne16(t.x) | (rne16(t.y) << 16), rne16(t.z) | (rne16(t.w) << 16));
}
__device__ __forceinline__ void unp2(unsigned u, float& a, float& b) {
    a = __uint_as_float(u << 16);
    b = __uint_as_float(u & 0xffff0000u);
}

// ---------------------------------------------------------------- kernel 1: LN (LN1 and LN2)
__global__ __launch_bounds__(256) void ln1_kernel(
    const float* __restrict__ x, const float* __restrict__ g,
    const float* __restrict__ b, float* __restrict__ xn) {
    const int row = blockIdx.x;
    const int t = threadIdx.x;
    const float* xr = x + row * D_;
    float x0 = xr[t], x1 = xr[t + 256];
    __shared__ float red[4];
    float s = waveReduceSum(x0 + x1);
    int lane = t & 63, wid = t >> 6;
    if (lane == 0) red[wid] = s;
    __syncthreads();
    float mean = (red[0] + red[1] + red[2] + red[3]) * (1.0f / D_);
    __syncthreads();
    float d0 = x0 - mean, d1 = x1 - mean;
    float v = waveReduceSum(d0 * d0 + d1 * d1);
    if (lane == 0) red[wid] = v;
    __syncthreads();
    float var = (red[0] + red[1] + red[2] + red[3]) * (1.0f / D_);
    float rs = rsqrtf(var + 1e-5f);
    xn[row * D_ + t]       = d0 * rs * g[t] + b[t];
    xn[row * D_ + t + 256] = d1 * rs * g[t + 256] + b[t + 256];
}

// ---------------------------------------------------------------- kernel 2: projections GEMM
__global__ __launch_bounds__(256) void proj_kernel(
    const float* __restrict__ xn, const float* __restrict__ coords,
    const float* __restrict__ Wq, const float* __restrict__ Wk, const float* __restrict__ Wv,
    const float* __restrict__ Wqp, const float* __restrict__ bqp,
    const float* __restrict__ Wkp, const float* __restrict__ bkp,
    const float* __restrict__ Wvp, const float* __restrict__ bvp,
    float* __restrict__ q, float* __restrict__ k, float* __restrict__ v,
    float* __restrict__ qp, float* __restrict__ kp, float* __restrict__ vp) {
    const int tid = threadIdx.x;
    const int rowBase = blockIdx.y * 64;
    const int colBase = blockIdx.x * 64;

    const float* Wseg; int ldw, segBase, segId;
    if      (colBase < 512)  { Wseg = Wq;  ldw = D_;   segBase = 0;    segId = 0; }
    else if (colBase < 1024) { Wseg = Wk;  ldw = D_;   segBase = 512;  segId = 1; }
    else if (colBase < 1536) { Wseg = Wv;  ldw = D_;   segBase = 1024; segId = 2; }
    else if (colBase < 1920) { Wseg = Wqp; ldw = HP3_; segBase = 1536; segId = 3; }
    else if (colBase < 2304) { Wseg = Wkp; ldw = HP3_; segBase = 1920; segId = 4; }
    else                     { Wseg = Wvp; ldw = HP3_; segBase = 2304; segId = 5; }
    const int segc0 = colBase - segBase;

    __shared__ float As[16][65];
    __shared__ float Bs[16][64];
    const int tx = tid & 15, ty = tid >> 4;

    float acc[4][4];
#pragma unroll
    for (int i = 0; i < 4; i++)
#pragma unroll
        for (int j = 0; j < 4; j++) acc[i][j] = 0.f;

    for (int k0 = 0; k0 < D_; k0 += 16) {
#pragma unroll
        for (int i = 0; i < 4; i++) {
            int e = tid + i * 256;
            int r = e >> 4, kk = e & 15;
            As[kk][r] = xn[(rowBase + r) * D_ + k0 + kk];
            int c = e & 63, kb = e >> 6;
            Bs[kb][c] = Wseg[(k0 + kb) * ldw + segc0 + c];
        }
        __syncthreads();
#pragma unroll
        for (int kk = 0; kk < 16; kk++) {
            float a[4], bb[4];
#pragma unroll
            for (int i = 0; i < 4; i++) a[i] = As[kk][ty * 4 + i];
#pragma unroll
            for (int j = 0; j < 4; j++) bb[j] = Bs[kk][tx * 4 + j];
#pragma unroll
            for (int i = 0; i < 4; i++)
#pragma unroll
                for (int j = 0; j < 4; j++) acc[i][j] = fmaf(a[i], bb[j], acc[i][j]);
        }
        __syncthreads();
    }

#pragma unroll
    for (int i = 0; i < 4; i++) {
        int r = rowBase + ty * 4 + i;
#pragma unroll
        for (int j = 0; j < 4; j++) {
            int lc = segc0 + tx * 4 + j;
            float val = acc[i][j];
            switch (segId) {
                case 0: q[r * D_ + lc] = val; break;
                case 1: k[r * D_ + lc] = val; break;
                case 2: v[r * D_ + lc] = val; break;
                case 3: qp[r * HP3_ + lc] = val + bqp[lc] + coords[r * 3 + lc % 3]; break;
                case 4: kp[r * HP3_ + lc] = val + bkp[lc] + coords[r * 3 + lc % 3]; break;
                case 5: vp[r * HP3_ + lc] = val + bvp[lc]; break;
            }
        }
    }
}

// ---------------------------------------------------------------- kernel 3: kn2 = sum(kp^2) per (b,s,h)
__global__ __launch_bounds__(256) void kn2_kernel(
    const float* __restrict__ kp, float* __restrict__ kn2) {
    int idx = blockIdx.x * 256 + threadIdx.x;
    const float* p = kp + idx * 48;
    float s = 0.f;
#pragma unroll
    for (int i = 0; i < 48; i++) s = fmaf(p[i], p[i], s);
    kn2[idx] = s;
}

// ---------------------------------------------------------------- kernel 4: flash attention
// LDS-BW-bound -> store K and V/VP as bf16 in LDS (one uint4 read = 8 dims);
// QP/KP stay fp32 (point term needs it). Online softmax is wave-local
// (m,l in registers per 16-lane q-group) -> 2 barriers per tile.
__global__ __launch_bounds__(256, 2) void attn_kernel(
    const float* __restrict__ q, const float* __restrict__ k, const float* __restrict__ v,
    const float* __restrict__ qp, const float* __restrict__ kp, const float* __restrict__ vp,
    const float* __restrict__ kn2, const float* __restrict__ coords,
    const float* __restrict__ Wd1, const float* __restrict__ bd1,
    const float* __restrict__ Wd2, const float* __restrict__ bd2,
    float* __restrict__ attn_out) {
    const int qt = blockIdx.x, h = blockIdx.y, b = blockIdx.z;
    const int tid = threadIdx.x;
    const int qpair = tid >> 4;        // 0..15
    const int sub = tid & 15;          // logits: key = sub+16j ; PV: dim-group = sub
    const int q0 = qpair * 2, q1 = q0 + 1;
    const int qbase = qt * QT;

    __shared__ __align__(16) float    sQ[QT * SQS];
    __shared__ __align__(16) float    sQP[QT * SQPS];
    __shared__ __align__(16) unsigned sKb[KT * SKBS];
    __shared__ __align__(16) float    sKP[KT * SKPS];
    __shared__ __align__(16) unsigned sVb[KT * SVBS];
    __shared__ __align__(16) float    sWt[QT * SWS];
    __shared__ float sCq[QT * 3], sCk[KT * 3], sKn2[KT];
    __shared__ float sW1[32], sB1[32], sW2h[32];

    const size_t bq = (size_t)(b * S_ + qbase);
    // ---- stage Q-side (once, fp32)
#pragma unroll
    for (int i = 0; i < 2; i++) {
        int f4 = tid + i * 256;           // 512 = 32x16
        int r = f4 >> 4, c = f4 & 15;
        *(float4*)&sQ[r * SQS + c * 4] = *(const float4*)(q + (bq + r) * D_ + h * DH_ + c * 4);
    }
    {
        int r = tid / 12, c = tid % 12;   // 384 = 32x12
        *(float4*)&sQP[r * SQPS + c * 4] = *(const float4*)(qp + (bq + r) * HP3_ + h * 48 + c * 4);
        if (tid < 128) {
            int f42 = tid + 256;
            int r2 = f42 / 12, c2 = f42 % 12;
            *(float4*)&sQP[r2 * SQPS + c2 * 4] = *(const float4*)(qp + (bq + r2) * HP3_ + h * 48 + c2 * 4);
        }
    }
    if (tid < QT * 3) sCq[tid] = coords[bq * 3 + tid];
    if (tid >= 128 && tid < 160) sW1[tid - 128] = Wd1[tid - 128];
    else if (tid >= 160 && tid < 192) sB1[tid - 160] = bd1[tid - 160];
    else if (tid >= 192 && tid < 224) sW2h[tid - 192] = Wd2[(tid - 192) * H_ + h];
    __syncthreads();

    // ---- per-lane Q-derived state (redundant across the 16 lanes of a group)
    float qn20 = 0.f, qn21 = 0.f;
#pragma unroll
    for (int i = 0; i < 12; i++) {
        float4 t0 = *(const float4*)&sQP[q0 * SQPS + i * 4];
        qn20 = dot4(t0, t0, qn20);
        float4 t1 = *(const float4*)&sQP[q1 * SQPS + i * 4];
        qn21 = dot4(t1, t1, qn21);
    }
    const float cqx0 = sCq[q0*3], cqy0 = sCq[q0*3+1], cqz0 = sCq[q0*3+2];
    const float cqx1 = sCq[q1*3], cqy1 = sCq[q1*3+1], cqz1 = sCq[q1*3+2];
    const float bd2h = bd2[h];

    float m0 = -3.0e38f, m1 = -3.0e38f, l0 = 0.f, l1 = 0.f;
    float o0[8] = {0,0,0,0,0,0,0,0}, o1[8] = {0,0,0,0,0,0,0,0};

    for (int kt = 0; kt < S_ / KT; kt++) {
        const size_t bk = (size_t)(b * S_ + kt * KT);
        // ---- stage K (bf16), KP (fp32), V|VP (bf16)
#pragma unroll
        for (int i = 0; i < 4; i++) {
            int f4 = tid + i * 256;       // 1024 = 64x16
            int r = f4 >> 4, c = f4 & 15;
            float4 t = *(const float4*)(k + (bk + r) * D_ + h * DH_ + c * 4);
            *(uint2*)&sKb[r * SKBS + c * 2] = pk4(t);
        }
#pragma unroll
        for (int i = 0; i < 3; i++) {
            int f4 = tid + i * 256;       // 768 = 64x12
            int r = f4 / 12, c = f4 % 12;
            *(float4*)&sKP[r * SKPS + c * 4] = *(const float4*)(kp + (bk + r) * HP3_ + h * 48 + c * 4);
        }
#pragma unroll
        for (int i = 0; i < 7; i++) {
            int f4 = tid + i * 256;       // 1792 = 64x28
            int r = f4 / 28, c4 = f4 % 28;
            float4 t;
            if (c4 < 16) t = *(const float4*)(v  + (bk + r) * D_   + h * DH_ + c4 * 4);
            else         t = *(const float4*)(vp + (bk + r) * HP3_ + h * 48  + (c4 - 16) * 4);
            *(uint2*)&sVb[r * SVBS + c4 * 2] = pk4(t);
        }
        if (tid < KT) sKn2[tid] = kn2[(bk + tid) * H_ + h];
        if (tid < KT * 3) sCk[tid] = coords[bk * 3 + tid];
        __syncthreads();                  // SYNC-K (all tiles staged)

        // ---- distances (2q x 4k, keys sub+16j)
        float ds0[4], ds1[4];
#pragma unroll
        for (int j = 0; j < 4; j++) {
            int kk = sub + 16 * j;
            float kx = sCk[kk*3], ky = sCk[kk*3+1], kz = sCk[kk*3+2];
            float dx = cqx0-kx, dy = cqy0-ky, dz = cqz0-kz;
            ds0[j] = sqrtf(fmaf(dx,dx,fmaf(dy,dy,dz*dz)));
            dx = cqx1-kx; dy = cqy1-ky; dz = cqz1-kz;
            ds1[j] = sqrtf(fmaf(dx,dx,fmaf(dy,dy,dz*dz)));
        }
        // ---- dist-MLP bias (pd folded into same accumulator below)
        float bias0[4], bias1[4];
#pragma unroll
        for (int j = 0; j < 4; j++) { bias0[j] = bd2h; bias1[j] = bd2h; }
#pragma unroll 4
        for (int jj = 0; jj < 32; jj++) {
            float w1 = sW1[jj], bb = sB1[jj], w2 = sW2h[jj];
#pragma unroll
            for (int j = 0; j < 4; j++) {
                float h0 = fmaf(ds0[j], w1, bb);
                float h1 = fmaf(ds1[j], w1, bb);
                bias0[j] = fmaf(fmaxf(h0, 0.f), w2, bias0[j]);
                bias1[j] = fmaf(fmaxf(h1, 0.f), w2, bias1[j]);
            }
        }
        // ---- qk dot: Q fp32, K bf16 (8 dims per uint4 read)
        float d0a[4] = {0,0,0,0}, d1a[4] = {0,0,0,0};
#pragma unroll 2
        for (int d8 = 0; d8 < 8; d8++) {
            float4 a0l = *(const float4*)&sQ[q0 * SQS + d8 * 8];
            float4 a0h = *(const float4*)&sQ[q0 * SQS + d8 * 8 + 4];
            float4 a1l = *(const float4*)&sQ[q1 * SQS + d8 * 8];
            float4 a1h = *(const float4*)&sQ[q1 * SQS + d8 * 8 + 4];
#pragma unroll
            for (int j = 0; j < 4; j++) {
                uint4 kw = *(const uint4*)&sKb[(sub + 16 * j) * SKBS + d8 * 4];
                float k0,k1,k2,k3,k4,k5,k6,k7;
                unp2(kw.x,k0,k1); unp2(kw.y,k2,k3); unp2(kw.z,k4,k5); unp2(kw.w,k6,k7);
                d0a[j] = fmaf(a0l.x,k0,fmaf(a0l.y,k1,fmaf(a0l.z,k2,fmaf(a0l.w,k3,d0a[j]))));
                d0a[j] = fmaf(a0h.x,k4,fmaf(a0h.y,k5,fmaf(a0h.z,k6,fmaf(a0h.w,k7,d0a[j]))));
                d1a[j] = fmaf(a1l.x,k0,fmaf(a1l.y,k1,fmaf(a1l.z,k2,fmaf(a1l.w,k3,d1a[j]))));
                d1a[j] = fmaf(a1h.x,k4,fmaf(a1h.y,k5,fmaf(a1h.z,k6,fmaf(a1h.w,k7,d1a[j]))));
            }
        }
        // ---- point dot (fp32), folded into bias accumulators
#pragma unroll 4
        for (int d4 = 0; d4 < 12; d4++) {
            float4 a0 = *(const float4*)&sQP[q0 * SQPS + d4 * 4];
            float4 a1 = *(const float4*)&sQP[q1 * SQPS + d4 * 4];
#pragma unroll
            for (int j = 0; j < 4; j++) {
                float4 bv = *(const float4*)&sKP[(sub + 16 * j) * SKPS + d4 * 4];
                bias0[j] = dot4(a0, bv, bias0[j]);
                bias1[j] = dot4(a1, bv, bias1[j]);
            }
        }
        // ---- logits + mask
        float lg0[4], lg1[4];
#pragma unroll
        for (int j = 0; j < 4; j++) {
            float kn = sKn2[sub + 16 * j];
            float v0 = fmaf(SCALE_, d0a[j], bias0[j]) - 0.5f * (qn20 + kn);
            float v1 = fmaf(SCALE_, d1a[j], bias1[j]) - 0.5f * (qn21 + kn);
            lg0[j] = (ds0[j] < CUTOFF) ? v0 : -1e9f;
            lg1[j] = (ds1[j] < CUTOFF) ? v1 : -1e9f;
        }
        // ---- wave-local online softmax (m,l in registers, identical across group)
        float t0 = fmaxf(fmaxf(lg0[0], lg0[1]), fmaxf(lg0[2], lg0[3]));
        float t1 = fmaxf(fmaxf(lg1[0], lg1[1]), fmaxf(lg1[2], lg1[3]));
#pragma unroll
        for (int off = 1; off < 16; off <<= 1) {
            t0 = fmaxf(t0, __shfl_xor(t0, off, 16));
            t1 = fmaxf(t1, __shfl_xor(t1, off, 16));
        }
        const float nm0 = fmaxf(m0, t0), nm1 = fmaxf(m1, t1);
        const float sc0 = __expf(m0 - nm0), sc1 = __expf(m1 - nm1);
        m0 = nm0; m1 = nm1;
        float ps0 = 0.f, ps1 = 0.f;
#pragma unroll
        for (int j = 0; j < 4; j++) {
            float w0 = __expf(lg0[j] - nm0);
            float w1 = __expf(lg1[j] - nm1);
            sWt[q0 * SWS + sub + 16 * j] = w0;   // same-wave write -> read below
            sWt[q1 * SWS + sub + 16 * j] = w1;
            ps0 += w0; ps1 += w1;
        }
#pragma unroll
        for (int off = 1; off < 16; off <<= 1) {
            ps0 += __shfl_xor(ps0, off, 16);
            ps1 += __shfl_xor(ps1, off, 16);
        }
        l0 = l0 * sc0 + ps0;
        l1 = l1 * sc1 + ps1;

        // ---- PV: 2q x 8 dims (group sub<14), V bf16: 1 uint4 per key
#pragma unroll
        for (int j = 0; j < 8; j++) { o0[j] *= sc0; o1[j] *= sc1; }
        if (sub < 14) {
            for (int kk4 = 0; kk4 < 16; kk4++) {
                float w0a[4], w1a[4];
                *(float4*)w0a = *(const float4*)&sWt[q0 * SWS + kk4 * 4];
                *(float4*)w1a = *(const float4*)&sWt[q1 * SWS + kk4 * 4];
#pragma unroll
                for (int jj = 0; jj < 4; jj++) {
                    int kk = kk4 * 4 + jj;
                    uint4 vw = *(const uint4*)&sVb[kk * SVBS + sub * 4];
                    float v0,v1,v2,v3,v4,v5,v6,v7;
                    unp2(vw.x,v0,v1); unp2(vw.y,v2,v3); unp2(vw.z,v4,v5); unp2(vw.w,v6,v7);
                    float w0 = w0a[jj], w1 = w1a[jj];
                    o0[0]=fmaf(w0,v0,o0[0]); o0[1]=fmaf(w0,v1,o0[1]);
                    o0[2]=fmaf(w0,v2,o0[2]); o0[3]=fmaf(w0,v3,o0[3]);
                    o0[4]=fmaf(w0,v4,o0[4]); o0[5]=fmaf(w0,v5,o0[5]);
                    o0[6]=fmaf(w0,v6,o0[6]); o0[7]=fmaf(w0,v7,o0[7]);
                    o1[0]=fmaf(w1,v0,o1[0]); o1[1]=fmaf(w1,v1,o1[1]);
                    o1[2]=fmaf(w1,v2,o1[2]); o1[3]=fmaf(w1,v3,o1[3]);
                    o1[4]=fmaf(w1,v4,o1[4]); o1[5]=fmaf(w1,v5,o1[5]);
                    o1[6]=fmaf(w1,v6,o1[6]); o1[7]=fmaf(w1,v7,o1[7]);
                }
            }
        }
        __syncthreads();                  // SYNC-C (before next staging overwrites)
    }

    // ---- epilogue
    if (sub < 14) {
        const int db = sub * 8;
        const float il0 = 1.0f / l0, il1 = 1.0f / l1;
        const int off = (db < 64) ? (h * 64 + db) : (512 + h * 48 + (db - 64));
        float* r0 = attn_out + (size_t)(bq + q0) * CONCAT_ + off;
        float* r1 = attn_out + (size_t)(bq + q1) * CONCAT_ + off;
        float4 w0a, w0b, w1a, w1b;
        w0a.x=o0[0]*il0; w0a.y=o0[1]*il0; w0a.z=o0[2]*il0; w0a.w=o0[3]*il0;
        w0b.x=o0[4]*il0; w0b.y=o0[5]*il0; w0b.z=o0[6]*il0; w0b.w=o0[7]*il0;
        w1a.x=o1[0]*il1; w1a.y=o1[1]*il1; w1a.z=o1[2]*il1; w1a.w=o1[3]*il1;
        w1b.x=o1[4]*il1; w1b.y=o1[5]*il1; w1b.z=o1[6]*il1; w1b.w=o1[7]*il1;
        *(float4*)r0 = w0a; *(float4*)(r0 + 4) = w0b;
        *(float4*)r1 = w1a; *(float4*)(r1 + 4) = w1b;
    }
}

// ---------------------------------------------------------------- kernel 5: out projection GEMM (+bias+residual)
__global__ __launch_bounds__(256) void ogemm_kernel(
    const float* __restrict__ aout, const float* __restrict__ x,
    const float* __restrict__ Wo, const float* __restrict__ bo,
    float* __restrict__ yres) {
    const int tid = threadIdx.x;
    const int rowBase = blockIdx.y * 64;
    const int colBase = blockIdx.x * 64;

    __shared__ float As[16][65];
    __shared__ float Bs[16][64];
    const int tx = tid & 15, ty = tid >> 4;

    float acc[4][4];
#pragma unroll
    for (int i = 0; i < 4; i++)
#pragma unroll
        for (int j = 0; j < 4; j++) acc[i][j] = 0.f;

    for (int k0 = 0; k0 < CONCAT_; k0 += 16) {
#pragma unroll
        for (int i = 0; i < 4; i++) {
            int e = tid + i * 256;
            int r = e >> 4, kk = e & 15;
            As[kk][r] = aout[(size_t)(rowBase + r) * CONCAT_ + k0 + kk];
            int c = e & 63, kb = e >> 6;
            Bs[kb][c] = Wo[(k0 + kb) * D_ + colBase + c];
        }
        __syncthreads();
#pragma unroll
        for (int kk = 0; kk < 16; kk++) {
            float a[4], bb[4];
#pragma unroll
            for (int i = 0; i < 4; i++) a[i] = As[kk][ty * 4 + i];
#pragma unroll
            for (int j = 0; j < 4; j++) bb[j] = Bs[kk][tx * 4 + j];
#pragma unroll
            for (int i = 0; i < 4; i++)
#pragma unroll
                for (int j = 0; j < 4; j++) acc[i][j] = fmaf(a[i], bb[j], acc[i][j]);
        }
        __syncthreads();
    }

#pragma unroll
    for (int i = 0; i < 4; i++) {
        int r = rowBase + ty * 4 + i;
#pragma unroll
        for (int j = 0; j < 4; j++) {
            int lc = colBase + tx * 4 + j;
            yres[(size_t)r * D_ + lc] = acc[i][j] + bo[lc] + x[(size_t)r * D_ + lc];
        }
    }
}

// ---------------------------------------------------------------- kernel 6: coord update
__global__ __launch_bounds__(64) void coord_kernel(
    const float* __restrict__ aout, const float* __restrict__ coords,
    float* __restrict__ coords_out) {
    const int row = blockIdx.x;
    const int t = threadIdx.x;
    const float* ap = aout + (size_t)row * CONCAT_ + 512;
    float c0 = ap[t * 3]     + ap[(t + 64) * 3];
    float c1 = ap[t * 3 + 1] + ap[(t + 64) * 3 + 1];
    float c2 = ap[t * 3 + 2] + ap[(t + 64) * 3 + 2];
#pragma unroll
    for (int o = 32; o; o >>= 1) {
        c0 += __shfl_down(c0, o, 64);
        c1 += __shfl_down(c1, o, 64);
        c2 += __shfl_down(c2, o, 64);
    }
    if (t == 0) {
        coords_out[row * 3 + 0] = coords[row * 3 + 0] + c0 * (0.1f / 128.f);
        coords_out[row * 3 + 1] = coords[row * 3 + 1] + c1 * (0.1f / 128.f);
        coords_out[row * 3 + 2] = coords[row * 3 + 2] + c2 * (0.1f / 128.f);
    }
}

// ---------------------------------------------------------------- launch
extern "C" void kernel_launch(void* const* d_in, const int* in_sizes, int n_in,
                              void* d_out, int out_size, void* d_ws, size_t ws_size,
                              hipStream_t stream) {
    const float* x      = (const float*)d_in[0];
    const float* coords = (const float*)d_in[1];
    const float* Wq     = (const float*)d_in[2];
    const float* Wk     = (const float*)d_in[3];
    const float* Wv     = (const float*)d_in[4];
    const float* Wqp    = (const float*)d_in[5];
    const float* bqp    = (const float*)d_in[6];
    const float* Wkp    = (const float*)d_in[7];
    const float* bkp    = (const float*)d_in[8];
    const float* Wvp    = (const float*)d_in[9];
    const float* bvp    = (const float*)d_in[10];
    const float* Wd1    = (const float*)d_in[11];
    const float* bd1    = (const float*)d_in[12];
    const float* Wd2    = (const float*)d_in[13];
    const float* bd2    = (const float*)d_in[14];
    const float* Wo     = (const float*)d_in[15];
    const float* bo     = (const float*)d_in[16];
    const float* g1     = (const float*)d_in[17];
    const float* b1     = (const float*)d_in[18];
    const float* g2     = (const float*)d_in[19];
    const float* b2     = (const float*)d_in[20];

    float* out        = (float*)d_out;
    float* coords_out = (float*)d_out + (size_t)B_ * S_ * D_;

    float* ws = (float*)d_ws;
    const size_t NROW = (size_t)B_ * S_;
    float* xn   = ws;                    // reused as yres after proj
    float* q    = xn   + NROW * D_;
    float* k    = q    + NROW * D_;
    float* v    = k    + NROW * D_;
    float* qp   = v    + NROW * D_;
    float* kp   = qp   + NROW * HP3_;
    float* vp   = kp   + NROW * HP3_;
    float* kn2  = vp   + NROW * HP3_;
    float* aout = kn2  + NROW * H_;

    ln1_kernel<<<NROW, 256, 0, stream>>>(x, g1, b1, xn);

    dim3 pgrid(2688 / 64, 2048 / 64);
    proj_kernel<<<pgrid, 256, 0, stream>>>(xn, coords, Wq, Wk, Wv,
                                           Wqp, bqp, Wkp, bkp, Wvp, bvp,
                                           q, k, v, qp, kp, vp);

    kn2_kernel<<<(NROW * H_) / 256, 256, 0, stream>>>(kp, kn2);

    dim3 agrid(S_ / QT, H_, B_);
    attn_kernel<<<agrid, 256, 0, stream>>>(q, k, v, qp, kp, vp, kn2, coords,
                                           Wd1, bd1, Wd2, bd2, aout);

    float* yres = xn;
    dim3 ogrid(D_ / 64, 2048 / 64);
    ogemm_kernel<<<ogrid, 256, 0, stream>>>(aout, x, Wo, bo, yres);

    ln1_kernel<<<NROW, 256, 0, stream>>>(yres, g2, b2, out);

    coord_kernel<<<NROW, 64, 0, stream>>>(aout, coords, coords_out);
}